// Round 1
// 297.394 us; speedup vs baseline: 1.0031x; 1.0031x over previous
//
#include <hip/hip_runtime.h>
#include <hip/hip_bf16.h>

#define D 128
#define EPS 1e-5f
#define CHK 8192            // edges per phase-1 chunk
#define P2CAP 6144          // max edges per 256-dst bucket

typedef __attribute__((ext_vector_type(8))) short short8;
typedef __attribute__((ext_vector_type(4))) float float4v;

__device__ inline ushort f2bf(float f) {
    __hip_bfloat16 b = __float2bfloat16(f);
    return *reinterpret_cast<ushort*>(&b);
}
__device__ inline float bf_lo(uint u) { return __uint_as_float(u << 16); }
__device__ inline float bf_hi(uint u) { return __uint_as_float(u & 0xffff0000u); }

// ---------- K1: fused weight-convert (blocks 0..12) + LN1+ReLU (rest) ---------
// cvt: m==0 W_root, 1..8 W_rel[m-1], 9..12 W_mlp[m-9] -> bf16 B-fragment order.
__global__ void k_ln1cvt(const float* __restrict__ x, const int* __restrict__ ntp,
                         const float* __restrict__ gamma, const float* __restrict__ beta,
                         ushort* __restrict__ y,
                         const float* __restrict__ Wrel, const float* __restrict__ Wroot,
                         const float* __restrict__ Wmlp, ushort* __restrict__ Wt, int N) {
    __shared__ ushort t[128][136];
    if (blockIdx.x < 13) {
        int m = blockIdx.x;
        const float* src = (m == 0) ? Wroot
                         : (m <= 8) ? Wrel + (size_t)(m - 1) * D * D
                                    : Wmlp + (size_t)(m - 9) * D * D;
        for (int i = threadIdx.x; i < D * D; i += 256) {
            int k = i >> 7, n = i & 127;
            t[n][k] = f2bf(src[i]);
        }
        __syncthreads();
        ushort* dst = Wt + (size_t)m * D * D;
        for (int i = threadIdx.x; i < D * D; i += 256) {
            int frag = i >> 9;
            int lane = (i >> 3) & 63;
            int j = i & 7;
            int nt = frag >> 2, ks = frag & 3;
            int n = nt * 16 + (lane & 15);
            int k = ks * 32 + (lane >> 4) * 8 + j;
            dst[i] = t[n][k];
        }
        return;
    }
    int n = (blockIdx.x - 13) * 4 + (threadIdx.x >> 6);
    if (n >= N) return;
    int l = threadIdx.x & 63;
    float2 v = *(const float2*)(x + (size_t)n * D + 2 * l);
    float s = v.x + v.y, s2 = v.x * v.x + v.y * v.y;
    #pragma unroll
    for (int o = 32; o; o >>= 1) { s += __shfl_xor(s, o, 64); s2 += __shfl_xor(s2, o, 64); }
    float mu = s * (1.0f / D);
    float var = s2 * (1.0f / D) - mu * mu;
    float inv = rsqrtf(var + EPS);
    int tt = ntp[n];
    float2 g = *(const float2*)(gamma + tt * D + 2 * l);
    float2 b = *(const float2*)(beta + tt * D + 2 * l);
    float a0 = fmaxf((v.x - mu) * inv * g.x + b.x, 0.0f);
    float a1 = fmaxf((v.y - mu) * inv * g.y + b.y, 0.0f);
    ((uint*)(y + (size_t)n * D))[l] = ((uint)f2bf(a1) << 16) | f2bf(a0);
}

// ---------- two-phase edge sort by dst (block-owned write regions) ------------
__global__ void k_c1(const int* __restrict__ edst, int* __restrict__ hist, int E, int B) {
    __shared__ int cnt[256];
    int c = blockIdx.x, tid = threadIdx.x;
    cnt[tid] = 0;
    __syncthreads();
    #pragma unroll 4
    for (int k = 0; k < CHK / 256; ++k) {
        int e = c * CHK + k * 256 + tid;
        if (e < E) atomicAdd(&cnt[edst[e] >> 8], 1);
    }
    __syncthreads();
    if (tid < B) hist[c * B + tid] = cnt[tid];
}
__global__ void k_c2(const int* __restrict__ hist, int* __restrict__ chunkoff,
                     int* __restrict__ bucktot, int C, int B) {
    __shared__ int v[128];
    int b = blockIdx.x, t = threadIdx.x;
    v[t] = (t < C) ? hist[t * B + b] : 0;
    __syncthreads();
    if (t == 0) {
        int s = 0;
        for (int c = 0; c < C; ++c) { int x = v[c]; v[c] = s; s += x; }
        bucktot[b] = s;
    }
    __syncthreads();
    if (t < C) chunkoff[t * B + b] = v[t];
}
// p1s: scatter edges into bucket-major edata; in-block scan of bucktot -> base
__global__ void k_p1s(const int* __restrict__ edst, const int* __restrict__ esrc,
                      const int* __restrict__ etyp, const int* __restrict__ bucktot,
                      const int* __restrict__ chunkoff, uint* __restrict__ edata,
                      int E, int B) {
    __shared__ int ps[256];
    __shared__ int base[256];
    __shared__ int cnt[256];
    int c = blockIdx.x, tid = threadIdx.x;
    int bt = (tid < B) ? bucktot[tid] : 0;
    ps[tid] = bt;
    __syncthreads();
    for (int o = 1; o < 256; o <<= 1) {
        int v = (tid >= o) ? ps[tid - o] : 0;
        __syncthreads();
        ps[tid] += v;
        __syncthreads();
    }
    base[tid] = (ps[tid] - bt) + ((tid < B) ? chunkoff[c * B + tid] : 0);
    cnt[tid] = 0;
    __syncthreads();
    #pragma unroll 4
    for (int k = 0; k < CHK / 256; ++k) {
        int e = c * CHK + k * 256 + tid;
        if (e < E) {
            int d = edst[e];
            int b = d >> 8;
            int r = atomicAdd(&cnt[b], 1);
            edata[base[b] + r] =
                ((uint)esrc[e] << 12) | ((uint)(d & 255) << 4) | (uint)etyp[e];
        }
    }
}
// p2: exact counting-sort within each 256-dst bucket; in-block scan for j0
__global__ void k_p2(const uint* __restrict__ edata, const int* __restrict__ bucktot,
                     uint* __restrict__ epack, int* __restrict__ offs,
                     int N, int E, int B) {
    __shared__ int ps[256];
    __shared__ uint ed[P2CAP];
    __shared__ int cnt[256], off[256], cur[256];
    int b = blockIdx.x, tid = threadIdx.x;
    int bt = (tid < B) ? bucktot[tid] : 0;
    ps[tid] = bt;
    __syncthreads();
    for (int o = 1; o < 256; o <<= 1) {
        int v = (tid >= o) ? ps[tid - o] : 0;
        __syncthreads();
        ps[tid] += v;
        __syncthreads();
    }
    int j0 = ps[b] - ((b < B) ? bucktot[b] : 0);   // exclusive prefix of bucket b
    int count = ps[b] - j0;
    if (count > P2CAP) count = P2CAP;
    for (int i = tid; i < count; i += 256) ed[i] = edata[j0 + i];
    cnt[tid] = 0;
    __syncthreads();
    for (int i = tid; i < count; i += 256) atomicAdd(&cnt[(ed[i] >> 4) & 255], 1);
    __syncthreads();
    if (tid == 0) {
        int s = 0;
        for (int i = 0; i < 256; ++i) { off[i] = s; cur[i] = s; s += cnt[i]; }
    }
    __syncthreads();
    for (int i = tid; i < count; i += 256) {
        uint v = ed[i];
        int dl = (v >> 4) & 255;
        int r = atomicAdd(&cur[dl], 1);
        epack[j0 + r] = ((v & 15u) << 28) | (v >> 12);
    }
    int v = b * 256 + tid;
    if (v < N) offs[v] = j0 + off[tid];
    if (b == 0 && tid == 0) offs[N] = E;
}

// ---------- K3: z[v][r] = sum of y[src] over edges (dst=v, type=r) ------------
__global__ void k_zagg(const ushort* __restrict__ ybuf, const int* __restrict__ offs,
                       const uint* __restrict__ epack, ushort* __restrict__ zbuf, int N) {
    int wave = threadIdx.x >> 6;
    int l = threadIdx.x & 63;
    int v = blockIdx.x * 4 + wave;
    if (v >= N) return;
    float2 a0 = {0.f,0.f}, a1 = {0.f,0.f}, a2 = {0.f,0.f}, a3 = {0.f,0.f};
    float2 a4 = {0.f,0.f}, a5 = {0.f,0.f}, a6 = {0.f,0.f}, a7 = {0.f,0.f};
    const uint* yb = (const uint*)ybuf;
    int j = offs[v], e1 = offs[v + 1];

#define ZACC(P, U) do {                                                   \
        float lo = bf_lo(U), hi = bf_hi(U);                               \
        switch ((P) >> 28) {                                              \
            case 0: a0.x += lo; a0.y += hi; break;                        \
            case 1: a1.x += lo; a1.y += hi; break;                        \
            case 2: a2.x += lo; a2.y += hi; break;                        \
            case 3: a3.x += lo; a3.y += hi; break;                        \
            case 4: a4.x += lo; a4.y += hi; break;                        \
            case 5: a5.x += lo; a5.y += hi; break;                        \
            case 6: a6.x += lo; a6.y += hi; break;                        \
            default: a7.x += lo; a7.y += hi; break;                       \
        }                                                                 \
    } while (0)

    while (j < e1) {
        int chunk = min(64, e1 - j);
        uint pl = (j + l < e1) ? epack[j + l] : 0;
        int i = 0;
        for (; i + 3 < chunk; i += 4) {
            uint p0 = __shfl(pl, i, 64);
            uint p1 = __shfl(pl, i + 1, 64);
            uint p2 = __shfl(pl, i + 2, 64);
            uint p3 = __shfl(pl, i + 3, 64);
            uint u0 = yb[(size_t)(p0 & 0x0FFFFFFFu) * 64 + l];
            uint u1 = yb[(size_t)(p1 & 0x0FFFFFFFu) * 64 + l];
            uint u2 = yb[(size_t)(p2 & 0x0FFFFFFFu) * 64 + l];
            uint u3 = yb[(size_t)(p3 & 0x0FFFFFFFu) * 64 + l];
            ZACC(p0, u0); ZACC(p1, u1); ZACC(p2, u2); ZACC(p3, u3);
        }
        for (; i < chunk; ++i) {
            uint p = __shfl(pl, i, 64);
            uint u = yb[(size_t)(p & 0x0FFFFFFFu) * 64 + l];
            ZACC(p, u);
        }
        j += chunk;
    }
#undef ZACC
    uint* zrow = (uint*)(zbuf + (size_t)v * 1024);
    zrow[0 * 64 + l] = ((uint)f2bf(a0.y) << 16) | f2bf(a0.x);
    zrow[1 * 64 + l] = ((uint)f2bf(a1.y) << 16) | f2bf(a1.x);
    zrow[2 * 64 + l] = ((uint)f2bf(a2.y) << 16) | f2bf(a2.x);
    zrow[3 * 64 + l] = ((uint)f2bf(a3.y) << 16) | f2bf(a3.x);
    zrow[4 * 64 + l] = ((uint)f2bf(a4.y) << 16) | f2bf(a4.x);
    zrow[5 * 64 + l] = ((uint)f2bf(a5.y) << 16) | f2bf(a5.x);
    zrow[6 * 64 + l] = ((uint)f2bf(a6.y) << 16) | f2bf(a6.x);
    zrow[7 * 64 + l] = ((uint)f2bf(a7.y) << 16) | f2bf(a7.x);
}

// ---------- K4: barrier-free conv-GEMM (K=1152) + LN2 + ReLU + MLP ------------
// One wave owns 32 rows (two 16-row groups); B-fragments are read DIRECTLY from
// L2-resident Wt (no LDS staging, no __syncthreads anywhere). A-fragments are
// double-buffered one mat ahead (aC/aN) so zbuf HBM latency hides under the
// 64-MFMA block of the previous mat. y2 tile is per-wave-private LDS (intra-wave
// write->read only). Each B-frag load feeds 2 MFMAs (both row groups).
__device__ __forceinline__ void aload4(short8 (&d)[2][4], const ushort* p0,
                                       const ushort* p1, int off, int ao) {
    #pragma unroll
    for (int ks = 0; ks < 4; ++ks) {
        d[0][ks] = *(const short8*)(p0 + off + ks * 32 + ao);
        d[1][ks] = *(const short8*)(p1 + off + ks * 32 + ao);
    }
}
__device__ __forceinline__ void mm2x8(float4v (&acc)[2][8], const short8 (&a)[2][4],
                                      const ushort* __restrict__ wp, int lane) {
    #pragma unroll
    for (int nt = 0; nt < 8; ++nt) {
        #pragma unroll
        for (int ks = 0; ks < 4; ++ks) {
            short8 b = *(const short8*)(wp + (((nt * 4 + ks) * 64 + lane) << 3));
            acc[0][nt] = __builtin_amdgcn_mfma_f32_16x16x32_bf16(a[0][ks], b, acc[0][nt], 0, 0, 0);
            acc[1][nt] = __builtin_amdgcn_mfma_f32_16x16x32_bf16(a[1][ks], b, acc[1][nt], 0, 0, 0);
        }
    }
}

__launch_bounds__(128, 2)
__global__ void k_gm(const ushort* __restrict__ ybuf, const ushort* __restrict__ zbuf,
                     const ushort* __restrict__ Wt, const float* __restrict__ x,
                     const int* __restrict__ ntp,
                     const float* __restrict__ gamma, const float* __restrict__ beta,
                     const float* __restrict__ bmlp, float* __restrict__ out, int N) {
    __shared__ ushort ysm[2][32][136];                  // per-wave-private y2 tiles
    int tid = threadIdx.x;
    int wave = tid >> 6, lane = tid & 63;
    int quad = lane >> 4, l15 = lane & 15;
    int ao = quad * 8;
    int base = blockIdx.x * 64 + wave * 32;             // 32 rows per wave

    const ushort* yrow0 = ybuf + (size_t)min(base + l15,      N - 1) * 128;
    const ushort* yrow1 = ybuf + (size_t)min(base + 16 + l15, N - 1) * 128;
    const ushort* zrow0 = zbuf + (size_t)min(base + l15,      N - 1) * 1024;
    const ushort* zrow1 = zbuf + (size_t)min(base + 16 + l15, N - 1) * 1024;

    float4v acc[2][8];
    #pragma unroll
    for (int g = 0; g < 2; ++g)
        #pragma unroll
        for (int nt = 0; nt < 8; ++nt) acc[g][nt] = (float4v){0.f, 0.f, 0.f, 0.f};

    // conv GEMM over 9 mats, A double-buffered one mat ahead
    short8 aC[2][4], aN[2][4];
    aload4(aC, yrow0, yrow1, 0, ao);                    // mat 0 A (ybuf)
    aload4(aN, zrow0, zrow1, 0, ao);                    // mat 1 A (z slot 0)
    mm2x8(acc, aC, Wt, lane);                           // mat 0
    #pragma unroll
    for (int mm = 0; mm < 4; ++mm) {
        aload4(aC, zrow0, zrow1, (2 * mm + 1) * 128, ao);        // mat 2mm+2 A
        mm2x8(acc, aN, Wt + (size_t)(2 * mm + 1) * 16384, lane); // mat 2mm+1
        if (mm < 3) aload4(aN, zrow0, zrow1, (2 * mm + 2) * 128, ao); // mat 2mm+3 A
        mm2x8(acc, aC, Wt + (size_t)(2 * mm + 2) * 16384, lane); // mat 2mm+2
    }

    // epilogue per group: x2 = x + acc (kept in acc); LN2 + ReLU -> y2 tile
    int ty[2][4];
    #pragma unroll
    for (int g = 0; g < 2; ++g) {
        int gb = base + g * 16;
        float s[4] = {0.f, 0.f, 0.f, 0.f}, s2[4] = {0.f, 0.f, 0.f, 0.f};
        #pragma unroll
        for (int nt = 0; nt < 8; ++nt) {
            int col = nt * 16 + l15;
            #pragma unroll
            for (int r = 0; r < 4; ++r) {
                int row = gb + quad * 4 + r;
                float xv = (row < N) ? x[(size_t)row * D + col] : 0.f;
                float t = acc[g][nt][r] + xv;
                acc[g][nt][r] = t;
                s[r] += t; s2[r] += t * t;
            }
        }
        #pragma unroll
        for (int r = 0; r < 4; ++r) {
            #pragma unroll
            for (int o = 1; o < 16; o <<= 1) {
                s[r]  += __shfl_xor(s[r],  o, 64);
                s2[r] += __shfl_xor(s2[r], o, 64);
            }
        }
        #pragma unroll
        for (int r = 0; r < 4; ++r) {
            int rc = min(gb + quad * 4 + r, N - 1);
            ty[g][r] = ntp[rc];
            float mu  = s[r] * (1.0f / D);
            float var = s2[r] * (1.0f / D) - mu * mu;
            float inv = rsqrtf(var + EPS);
            int lrow = g * 16 + quad * 4 + r;
            #pragma unroll
            for (int nt = 0; nt < 8; ++nt) {
                int col = nt * 16 + l15;
                float yn = fmaxf((acc[g][nt][r] - mu) * inv * gamma[ty[g][r] * D + col]
                                 + beta[ty[g][r] * D + col], 0.f);
                ysm[wave][lrow][col] = f2bf(yn);
            }
        }
    }
    // MLP A-fragments: intra-wave LDS read-back (own rows only, no barrier)
    short8 a2[2][4];
    #pragma unroll
    for (int g = 0; g < 2; ++g) {
        const ushort* myrow = &ysm[wave][g * 16 + l15][0];
        #pragma unroll
        for (int ks = 0; ks < 4; ++ks) a2[g][ks] = *(const short8*)(myrow + ks * 32 + ao);
    }

    const ushort* W0 = Wt + (size_t)9  * D * D;
    const ushort* W1 = Wt + (size_t)10 * D * D;
    const ushort* W2 = Wt + (size_t)11 * D * D;
    const ushort* W3 = Wt + (size_t)12 * D * D;
    #pragma unroll
    for (int nt = 0; nt < 8; ++nt) {
        float4v c[2][4];
        #pragma unroll
        for (int g = 0; g < 2; ++g)
            #pragma unroll
            for (int t = 0; t < 4; ++t) c[g][t] = (float4v){0.f, 0.f, 0.f, 0.f};
        #pragma unroll
        for (int ks = 0; ks < 4; ++ks) {
            int fo = ((nt * 4 + ks) * 64 + lane) << 3;
            short8 b0 = *(const short8*)(W0 + fo);
            short8 b1 = *(const short8*)(W1 + fo);
            short8 b2 = *(const short8*)(W2 + fo);
            short8 b3 = *(const short8*)(W3 + fo);
            #pragma unroll
            for (int g = 0; g < 2; ++g) {
                c[g][0] = __builtin_amdgcn_mfma_f32_16x16x32_bf16(a2[g][ks], b0, c[g][0], 0, 0, 0);
                c[g][1] = __builtin_amdgcn_mfma_f32_16x16x32_bf16(a2[g][ks], b1, c[g][1], 0, 0, 0);
                c[g][2] = __builtin_amdgcn_mfma_f32_16x16x32_bf16(a2[g][ks], b2, c[g][2], 0, 0, 0);
                c[g][3] = __builtin_amdgcn_mfma_f32_16x16x32_bf16(a2[g][ks], b3, c[g][3], 0, 0, 0);
            }
        }
        int col = nt * 16 + l15;
        #pragma unroll
        for (int g = 0; g < 2; ++g) {
            #pragma unroll
            for (int r = 0; r < 4; ++r) {
                int row = base + g * 16 + quad * 4 + r;
                if (row < N) {
                    int t = ty[g][r];
                    float v = (t == 0) ? c[g][0][r] : (t == 1) ? c[g][1][r]
                            : (t == 2) ? c[g][2][r] : c[g][3][r];
                    out[(size_t)row * D + col] = acc[g][nt][r] + v + bmlp[t * D + col];
                }
            }
        }
    }
}

// ---------- launch ------------------------------------------------------------
extern "C" void kernel_launch(void* const* d_in, const int* in_sizes, int n_in,
                              void* d_out, int out_size, void* d_ws, size_t ws_size,
                              hipStream_t stream) {
    const float* x          = (const float*)d_in[0];
    const int*   esrc       = (const int*)d_in[1];
    const int*   edst       = (const int*)d_in[2];
    const int*   ntyp       = (const int*)d_in[3];
    const int*   etyp       = (const int*)d_in[4];
    const float* conv_gamma = (const float*)d_in[5];
    const float* conv_beta  = (const float*)d_in[6];
    const float* W_rel      = (const float*)d_in[7];
    const float* W_root     = (const float*)d_in[8];
    const float* mlp_gamma  = (const float*)d_in[9];
    const float* mlp_beta   = (const float*)d_in[10];
    const float* W_mlp      = (const float*)d_in[11];
    const float* b_mlp      = (const float*)d_in[12];
    float* out = (float*)d_out;

    int N = in_sizes[0] / D;
    int E = in_sizes[1];
    int C = (E + CHK - 1) / CHK;        // chunks (<=128)
    int B = (N + 255) / 256;            // coarse buckets (<=256)

    char* p = (char*)d_ws;
    auto take = [&p](size_t bytes) { char* q = p; p += (bytes + 255) & ~(size_t)255; return q; };
    ushort* ybuf    = (ushort*)take((size_t)N * D * 2);
    ushort* zbuf    = (ushort*)take((size_t)N * 1024 * 2);
    ushort* Wt      = (ushort*)take((size_t)13 * D * D * 2);
    uint*   edata   = (uint*)take((size_t)E * 4);
    uint*   epack   = (uint*)take((size_t)E * 4);
    int*    offs    = (int*)take((size_t)(N + 1) * 4);
    int*    hist    = (int*)take((size_t)C * B * 4);
    int*    chunkoff= (int*)take((size_t)C * B * 4);
    int*    bucktot = (int*)take((size_t)B * 4);

    k_ln1cvt<<<13 + (N + 3) / 4, 256, 0, stream>>>(x, ntyp, conv_gamma, conv_beta,
                                                   ybuf, W_rel, W_root, W_mlp, Wt, N);

    k_c1<<<C, 256, 0, stream>>>(edst, hist, E, B);
    k_c2<<<B, 128, 0, stream>>>(hist, chunkoff, bucktot, C, B);
    k_p1s<<<C, 256, 0, stream>>>(edst, esrc, etyp, bucktot, chunkoff, edata, E, B);
    k_p2<<<B, 256, 0, stream>>>(edata, bucktot, epack, offs, N, E, B);

    k_zagg<<<(N + 3) / 4, 256, 0, stream>>>(ybuf, offs, epack, zbuf, N);

    k_gm<<<(N + 63) / 64, 128, 0, stream>>>(ybuf, zbuf, Wt, x, ntyp,
                                            mlp_gamma, mlp_beta, b_mlp, out, N);
}

// Round 2
// 292.289 us; speedup vs baseline: 1.0207x; 1.0175x over previous
//
#include <hip/hip_runtime.h>
#include <hip/hip_bf16.h>

#define D 128
#define EPS 1e-5f
#define CHK 8192            // edges per phase-1 chunk
#define P2CAP 6144          // max edges per 256-dst bucket

typedef __attribute__((ext_vector_type(8))) short short8;
typedef __attribute__((ext_vector_type(4))) float float4v;

__device__ inline ushort f2bf(float f) {
    __hip_bfloat16 b = __float2bfloat16(f);
    return *reinterpret_cast<ushort*>(&b);
}
__device__ inline float bf_lo(uint u) { return __uint_as_float(u << 16); }
__device__ inline float bf_hi(uint u) { return __uint_as_float(u & 0xffff0000u); }

// ---------- K1: fused weight-convert (blocks 0..12) + LN1+ReLU (rest) ---------
// cvt: m==0 W_root, 1..8 W_rel[m-1], 9..12 W_mlp[m-9] -> bf16 B-fragment order.
__global__ void k_ln1cvt(const float* __restrict__ x, const int* __restrict__ ntp,
                         const float* __restrict__ gamma, const float* __restrict__ beta,
                         ushort* __restrict__ y,
                         const float* __restrict__ Wrel, const float* __restrict__ Wroot,
                         const float* __restrict__ Wmlp, ushort* __restrict__ Wt, int N) {
    __shared__ ushort t[128][136];
    if (blockIdx.x < 13) {
        int m = blockIdx.x;
        const float* src = (m == 0) ? Wroot
                         : (m <= 8) ? Wrel + (size_t)(m - 1) * D * D
                                    : Wmlp + (size_t)(m - 9) * D * D;
        for (int i = threadIdx.x; i < D * D; i += 256) {
            int k = i >> 7, n = i & 127;
            t[n][k] = f2bf(src[i]);
        }
        __syncthreads();
        ushort* dst = Wt + (size_t)m * D * D;
        for (int i = threadIdx.x; i < D * D; i += 256) {
            int frag = i >> 9;
            int lane = (i >> 3) & 63;
            int j = i & 7;
            int nt = frag >> 2, ks = frag & 3;
            int n = nt * 16 + (lane & 15);
            int k = ks * 32 + (lane >> 4) * 8 + j;
            dst[i] = t[n][k];
        }
        return;
    }
    int n = (blockIdx.x - 13) * 4 + (threadIdx.x >> 6);
    if (n >= N) return;
    int l = threadIdx.x & 63;
    float2 v = *(const float2*)(x + (size_t)n * D + 2 * l);
    float s = v.x + v.y, s2 = v.x * v.x + v.y * v.y;
    #pragma unroll
    for (int o = 32; o; o >>= 1) { s += __shfl_xor(s, o, 64); s2 += __shfl_xor(s2, o, 64); }
    float mu = s * (1.0f / D);
    float var = s2 * (1.0f / D) - mu * mu;
    float inv = rsqrtf(var + EPS);
    int tt = ntp[n];
    float2 g = *(const float2*)(gamma + tt * D + 2 * l);
    float2 b = *(const float2*)(beta + tt * D + 2 * l);
    float a0 = fmaxf((v.x - mu) * inv * g.x + b.x, 0.0f);
    float a1 = fmaxf((v.y - mu) * inv * g.y + b.y, 0.0f);
    ((uint*)(y + (size_t)n * D))[l] = ((uint)f2bf(a1) << 16) | f2bf(a0);
}

// ---------- two-phase edge sort by dst (block-owned write regions) ------------
__global__ void k_c1(const int* __restrict__ edst, int* __restrict__ hist, int E, int B) {
    __shared__ int cnt[256];
    int c = blockIdx.x, tid = threadIdx.x;
    cnt[tid] = 0;
    __syncthreads();
    #pragma unroll 4
    for (int k = 0; k < CHK / 256; ++k) {
        int e = c * CHK + k * 256 + tid;
        if (e < E) atomicAdd(&cnt[edst[e] >> 8], 1);
    }
    __syncthreads();
    if (tid < B) hist[c * B + tid] = cnt[tid];
}
__global__ void k_c2(const int* __restrict__ hist, int* __restrict__ chunkoff,
                     int* __restrict__ bucktot, int C, int B) {
    __shared__ int v[128];
    int b = blockIdx.x, t = threadIdx.x;
    v[t] = (t < C) ? hist[t * B + b] : 0;
    __syncthreads();
    if (t == 0) {
        int s = 0;
        for (int c = 0; c < C; ++c) { int x = v[c]; v[c] = s; s += x; }
        bucktot[b] = s;
    }
    __syncthreads();
    if (t < C) chunkoff[t * B + b] = v[t];
}
// p1s: scatter edges into bucket-major edata; in-block scan of bucktot -> base
__global__ void k_p1s(const int* __restrict__ edst, const int* __restrict__ esrc,
                      const int* __restrict__ etyp, const int* __restrict__ bucktot,
                      const int* __restrict__ chunkoff, uint* __restrict__ edata,
                      int E, int B) {
    __shared__ int ps[256];
    __shared__ int base[256];
    __shared__ int cnt[256];
    int c = blockIdx.x, tid = threadIdx.x;
    int bt = (tid < B) ? bucktot[tid] : 0;
    ps[tid] = bt;
    __syncthreads();
    for (int o = 1; o < 256; o <<= 1) {
        int v = (tid >= o) ? ps[tid - o] : 0;
        __syncthreads();
        ps[tid] += v;
        __syncthreads();
    }
    base[tid] = (ps[tid] - bt) + ((tid < B) ? chunkoff[c * B + tid] : 0);
    cnt[tid] = 0;
    __syncthreads();
    #pragma unroll 4
    for (int k = 0; k < CHK / 256; ++k) {
        int e = c * CHK + k * 256 + tid;
        if (e < E) {
            int d = edst[e];
            int b = d >> 8;
            int r = atomicAdd(&cnt[b], 1);
            edata[base[b] + r] =
                ((uint)esrc[e] << 12) | ((uint)(d & 255) << 4) | (uint)etyp[e];
        }
    }
}
// p2: exact counting-sort within each 256-dst bucket; in-block scan for j0
__global__ void k_p2(const uint* __restrict__ edata, const int* __restrict__ bucktot,
                     uint* __restrict__ epack, int* __restrict__ offs,
                     int N, int E, int B) {
    __shared__ int ps[256];
    __shared__ uint ed[P2CAP];
    __shared__ int cnt[256], off[256], cur[256];
    int b = blockIdx.x, tid = threadIdx.x;
    int bt = (tid < B) ? bucktot[tid] : 0;
    ps[tid] = bt;
    __syncthreads();
    for (int o = 1; o < 256; o <<= 1) {
        int v = (tid >= o) ? ps[tid - o] : 0;
        __syncthreads();
        ps[tid] += v;
        __syncthreads();
    }
    int j0 = ps[b] - ((b < B) ? bucktot[b] : 0);   // exclusive prefix of bucket b
    int count = ps[b] - j0;
    if (count > P2CAP) count = P2CAP;
    for (int i = tid; i < count; i += 256) ed[i] = edata[j0 + i];
    cnt[tid] = 0;
    __syncthreads();
    for (int i = tid; i < count; i += 256) atomicAdd(&cnt[(ed[i] >> 4) & 255], 1);
    __syncthreads();
    if (tid == 0) {
        int s = 0;
        for (int i = 0; i < 256; ++i) { off[i] = s; cur[i] = s; s += cnt[i]; }
    }
    __syncthreads();
    for (int i = tid; i < count; i += 256) {
        uint v = ed[i];
        int dl = (v >> 4) & 255;
        int r = atomicAdd(&cur[dl], 1);
        epack[j0 + r] = ((v & 15u) << 28) | (v >> 12);
    }
    int v = b * 256 + tid;
    if (v < N) offs[v] = j0 + off[tid];
    if (b == 0 && tid == 0) offs[N] = E;
}

// ---------- K3: z[v][r] = sum of y[src] over edges (dst=v, type=r) ------------
__global__ void k_zagg(const ushort* __restrict__ ybuf, const int* __restrict__ offs,
                       const uint* __restrict__ epack, ushort* __restrict__ zbuf, int N) {
    int wave = threadIdx.x >> 6;
    int l = threadIdx.x & 63;
    int v = blockIdx.x * 4 + wave;
    if (v >= N) return;
    float2 a0 = {0.f,0.f}, a1 = {0.f,0.f}, a2 = {0.f,0.f}, a3 = {0.f,0.f};
    float2 a4 = {0.f,0.f}, a5 = {0.f,0.f}, a6 = {0.f,0.f}, a7 = {0.f,0.f};
    const uint* yb = (const uint*)ybuf;
    int j = offs[v], e1 = offs[v + 1];

#define ZACC(P, U) do {                                                   \
        float lo = bf_lo(U), hi = bf_hi(U);                               \
        switch ((P) >> 28) {                                              \
            case 0: a0.x += lo; a0.y += hi; break;                        \
            case 1: a1.x += lo; a1.y += hi; break;                        \
            case 2: a2.x += lo; a2.y += hi; break;                        \
            case 3: a3.x += lo; a3.y += hi; break;                        \
            case 4: a4.x += lo; a4.y += hi; break;                        \
            case 5: a5.x += lo; a5.y += hi; break;                        \
            case 6: a6.x += lo; a6.y += hi; break;                        \
            default: a7.x += lo; a7.y += hi; break;                       \
        }                                                                 \
    } while (0)

    while (j < e1) {
        int chunk = min(64, e1 - j);
        uint pl = (j + l < e1) ? epack[j + l] : 0;
        int i = 0;
        for (; i + 3 < chunk; i += 4) {
            uint p0 = __shfl(pl, i, 64);
            uint p1 = __shfl(pl, i + 1, 64);
            uint p2 = __shfl(pl, i + 2, 64);
            uint p3 = __shfl(pl, i + 3, 64);
            uint u0 = yb[(size_t)(p0 & 0x0FFFFFFFu) * 64 + l];
            uint u1 = yb[(size_t)(p1 & 0x0FFFFFFFu) * 64 + l];
            uint u2 = yb[(size_t)(p2 & 0x0FFFFFFFu) * 64 + l];
            uint u3 = yb[(size_t)(p3 & 0x0FFFFFFFu) * 64 + l];
            ZACC(p0, u0); ZACC(p1, u1); ZACC(p2, u2); ZACC(p3, u3);
        }
        for (; i < chunk; ++i) {
            uint p = __shfl(pl, i, 64);
            uint u = yb[(size_t)(p & 0x0FFFFFFFu) * 64 + l];
            ZACC(p, u);
        }
        j += chunk;
    }
#undef ZACC
    uint* zrow = (uint*)(zbuf + (size_t)v * 1024);
    zrow[0 * 64 + l] = ((uint)f2bf(a0.y) << 16) | f2bf(a0.x);
    zrow[1 * 64 + l] = ((uint)f2bf(a1.y) << 16) | f2bf(a1.x);
    zrow[2 * 64 + l] = ((uint)f2bf(a2.y) << 16) | f2bf(a2.x);
    zrow[3 * 64 + l] = ((uint)f2bf(a3.y) << 16) | f2bf(a3.x);
    zrow[4 * 64 + l] = ((uint)f2bf(a4.y) << 16) | f2bf(a4.x);
    zrow[5 * 64 + l] = ((uint)f2bf(a5.y) << 16) | f2bf(a5.x);
    zrow[6 * 64 + l] = ((uint)f2bf(a6.y) << 16) | f2bf(a6.x);
    zrow[7 * 64 + l] = ((uint)f2bf(a7.y) << 16) | f2bf(a7.x);
}

// ---------- K4: barrier-free conv-GEMM (K=1152) + LN2 + ReLU + MLP ------------
// Latency-hiding by REGISTER double-buffering (grid gives only ~1.5 waves/SIMD,
// so TLP can't hide L2 latency; buy MLP depth with VGPRs instead):
//  - conv: b0/b1 hold a half-mat (16 B-frags = 64 VGPR) each; each loadB16 is
//    issued one half-mat (32 MFMAs) before use. A (zbuf) prefetched ~2 mats
//    ahead (~600+ cyc) to cover L3 scatter latency.
//  - MLP: mb0/mb1 hold 8 frags (4 types x 2 ks); one stage ahead.
// All buffers statically indexed (full unroll) so nothing spills to scratch.
__device__ __forceinline__ void aload4(short8 (&d)[2][4], const ushort* p0,
                                       const ushort* p1, int off, int ao) {
    #pragma unroll
    for (int ks = 0; ks < 4; ++ks) {
        d[0][ks] = *(const short8*)(p0 + off + ks * 32 + ao);
        d[1][ks] = *(const short8*)(p1 + off + ks * 32 + ao);
    }
}
__device__ __forceinline__ void loadB16(short8 (&b)[16], const ushort* __restrict__ wp,
                                        int lane) {
    #pragma unroll
    for (int i = 0; i < 16; ++i)
        b[i] = *(const short8*)(wp + ((i * 64 + lane) << 3));
}
__device__ __forceinline__ void mmHalf(float4v (&acc)[2][8], const short8 (&a)[2][4],
                                       const short8 (&b)[16], int ntBase) {
    #pragma unroll
    for (int nt = 0; nt < 4; ++nt) {
        #pragma unroll
        for (int ks = 0; ks < 4; ++ks) {
            acc[0][ntBase + nt] = __builtin_amdgcn_mfma_f32_16x16x32_bf16(
                a[0][ks], b[nt * 4 + ks], acc[0][ntBase + nt], 0, 0, 0);
            acc[1][ntBase + nt] = __builtin_amdgcn_mfma_f32_16x16x32_bf16(
                a[1][ks], b[nt * 4 + ks], acc[1][ntBase + nt], 0, 0, 0);
        }
    }
}
__device__ __forceinline__ void loadM8(short8 (&b)[8], const ushort* __restrict__ Wm,
                                       int nt, int kh, int lane) {
    #pragma unroll
    for (int t = 0; t < 4; ++t)
        #pragma unroll
        for (int kk = 0; kk < 2; ++kk)
            b[t * 2 + kk] = *(const short8*)(Wm + (size_t)t * 16384 +
                              (((nt * 4 + kh * 2 + kk) * 64 + lane) << 3));
}
__device__ __forceinline__ void mmMlp(float4v (&c)[2][4], const short8 (&a2)[2][4],
                                      const short8 (&b)[8], int kh) {
    #pragma unroll
    for (int t = 0; t < 4; ++t) {
        #pragma unroll
        for (int kk = 0; kk < 2; ++kk) {
            int ks = kh * 2 + kk;
            c[0][t] = __builtin_amdgcn_mfma_f32_16x16x32_bf16(
                a2[0][ks], b[t * 2 + kk], c[0][t], 0, 0, 0);
            c[1][t] = __builtin_amdgcn_mfma_f32_16x16x32_bf16(
                a2[1][ks], b[t * 2 + kk], c[1][t], 0, 0, 0);
        }
    }
}

__launch_bounds__(128, 2)
__global__ void k_gm(const ushort* __restrict__ ybuf, const ushort* __restrict__ zbuf,
                     const ushort* __restrict__ Wt, const float* __restrict__ x,
                     const int* __restrict__ ntp,
                     const float* __restrict__ gamma, const float* __restrict__ beta,
                     const float* __restrict__ bmlp, float* __restrict__ out, int N) {
    __shared__ ushort ysm[2][32][140];   // pad 140: 16-bit stores hit all 32 banks
    int tid = threadIdx.x;
    int wave = tid >> 6, lane = tid & 63;
    int quad = lane >> 4, l15 = lane & 15;
    int ao = quad * 8;
    int base = blockIdx.x * 64 + wave * 32;             // 32 rows per wave

    const ushort* yrow0 = ybuf + (size_t)min(base + l15,      N - 1) * 128;
    const ushort* yrow1 = ybuf + (size_t)min(base + 16 + l15, N - 1) * 128;
    const ushort* zrow0 = zbuf + (size_t)min(base + l15,      N - 1) * 1024;
    const ushort* zrow1 = zbuf + (size_t)min(base + 16 + l15, N - 1) * 1024;

    float4v acc[2][8];
    #pragma unroll
    for (int g = 0; g < 2; ++g)
        #pragma unroll
        for (int nt = 0; nt < 8; ++nt) acc[g][nt] = (float4v){0.f, 0.f, 0.f, 0.f};

    // ---- conv GEMM over 9 mats: A 2-deep, B half-mat double-buffered ----
    short8 aC[2][4], aN[2][4];
    short8 b0[16], b1[16];
    aload4(aC, yrow0, yrow1, 0, ao);                    // A[0] (ybuf)
    loadB16(b0, Wt, lane);                              // mat0 half0
    aload4(aN, zrow0, zrow1, 0, ao);                    // A[1] (z slot 0)
    #pragma unroll
    for (int m = 0; m < 9; ++m) {
        short8 (&cur)[2][4] = (m & 1) ? aN : aC;        // holds A[m]
        const ushort* wb = Wt + (size_t)m * 16384;
        loadB16(b1, wb + 8192, lane);                   // mat m half1
        mmHalf(acc, cur, b0, 0);                        // compute half0
        if (m < 8) loadB16(b0, wb + 16384, lane);       // mat m+1 half0
        mmHalf(acc, cur, b1, 4);                        // compute half1 (last use of cur)
        if (m < 7) aload4(cur, zrow0, zrow1, (m + 1) * 128, ao);  // A[m+2]
    }

    // epilogue per group: x2 = x + acc (kept in acc); LN2 + ReLU -> y2 tile
    int ty[2][4];
    #pragma unroll
    for (int g = 0; g < 2; ++g) {
        int gb = base + g * 16;
        float s[4] = {0.f, 0.f, 0.f, 0.f}, s2[4] = {0.f, 0.f, 0.f, 0.f};
        #pragma unroll
        for (int nt = 0; nt < 8; ++nt) {
            int col = nt * 16 + l15;
            #pragma unroll
            for (int r = 0; r < 4; ++r) {
                int row = gb + quad * 4 + r;
                float xv = (row < N) ? x[(size_t)row * D + col] : 0.f;
                float t = acc[g][nt][r] + xv;
                acc[g][nt][r] = t;
                s[r] += t; s2[r] += t * t;
            }
        }
        #pragma unroll
        for (int r = 0; r < 4; ++r) {
            #pragma unroll
            for (int o = 1; o < 16; o <<= 1) {
                s[r]  += __shfl_xor(s[r],  o, 64);
                s2[r] += __shfl_xor(s2[r], o, 64);
            }
        }
        #pragma unroll
        for (int r = 0; r < 4; ++r) {
            int rc = min(gb + quad * 4 + r, N - 1);
            ty[g][r] = ntp[rc];
            float mu  = s[r] * (1.0f / D);
            float var = s2[r] * (1.0f / D) - mu * mu;
            float inv = rsqrtf(var + EPS);
            int lrow = g * 16 + quad * 4 + r;
            #pragma unroll
            for (int nt = 0; nt < 8; ++nt) {
                int col = nt * 16 + l15;
                float yn = fmaxf((acc[g][nt][r] - mu) * inv * gamma[ty[g][r] * D + col]
                                 + beta[ty[g][r] * D + col], 0.f);
                ysm[wave][lrow][col] = f2bf(yn);
            }
        }
    }
    // MLP A-fragments: intra-wave LDS read-back (own rows only, no barrier)
    short8 a2[2][4];
    #pragma unroll
    for (int g = 0; g < 2; ++g) {
        const ushort* myrow = &ysm[wave][g * 16 + l15][0];
        #pragma unroll
        for (int ks = 0; ks < 4; ++ks) a2[g][ks] = *(const short8*)(myrow + ks * 32 + ao);
    }

    // ---- MLP: 4-type variants, B pipelined one 8-frag stage ahead ----
    const ushort* Wm = Wt + (size_t)9 * 16384;
    short8 mb0[8], mb1[8];
    loadM8(mb0, Wm, 0, 0, lane);
    #pragma unroll
    for (int nt = 0; nt < 8; ++nt) {
        loadM8(mb1, Wm, nt, 1, lane);
        float4v c[2][4];
        #pragma unroll
        for (int g = 0; g < 2; ++g)
            #pragma unroll
            for (int t = 0; t < 4; ++t) c[g][t] = (float4v){0.f, 0.f, 0.f, 0.f};
        mmMlp(c, a2, mb0, 0);
        if (nt < 7) loadM8(mb0, Wm, nt + 1, 0, lane);
        mmMlp(c, a2, mb1, 1);
        int col = nt * 16 + l15;
        #pragma unroll
        for (int g = 0; g < 2; ++g) {
            #pragma unroll
            for (int r = 0; r < 4; ++r) {
                int row = base + g * 16 + quad * 4 + r;
                if (row < N) {
                    int t = ty[g][r];
                    float v = (t == 0) ? c[g][0][r] : (t == 1) ? c[g][1][r]
                            : (t == 2) ? c[g][2][r] : c[g][3][r];
                    out[(size_t)row * D + col] = acc[g][nt][r] + v + bmlp[t * D + col];
                }
            }
        }
    }
}

// ---------- launch ------------------------------------------------------------
extern "C" void kernel_launch(void* const* d_in, const int* in_sizes, int n_in,
                              void* d_out, int out_size, void* d_ws, size_t ws_size,
                              hipStream_t stream) {
    const float* x          = (const float*)d_in[0];
    const int*   esrc       = (const int*)d_in[1];
    const int*   edst       = (const int*)d_in[2];
    const int*   ntyp       = (const int*)d_in[3];
    const int*   etyp       = (const int*)d_in[4];
    const float* conv_gamma = (const float*)d_in[5];
    const float* conv_beta  = (const float*)d_in[6];
    const float* W_rel      = (const float*)d_in[7];
    const float* W_root     = (const float*)d_in[8];
    const float* mlp_gamma  = (const float*)d_in[9];
    const float* mlp_beta   = (const float*)d_in[10];
    const float* W_mlp      = (const float*)d_in[11];
    const float* b_mlp      = (const float*)d_in[12];
    float* out = (float*)d_out;

    int N = in_sizes[0] / D;
    int E = in_sizes[1];
    int C = (E + CHK - 1) / CHK;        // chunks (<=128)
    int B = (N + 255) / 256;            // coarse buckets (<=256)

    char* p = (char*)d_ws;
    auto take = [&p](size_t bytes) { char* q = p; p += (bytes + 255) & ~(size_t)255; return q; };
    ushort* ybuf    = (ushort*)take((size_t)N * D * 2);
    ushort* zbuf    = (ushort*)take((size_t)N * 1024 * 2);
    ushort* Wt      = (ushort*)take((size_t)13 * D * D * 2);
    uint*   edata   = (uint*)take((size_t)E * 4);
    uint*   epack   = (uint*)take((size_t)E * 4);
    int*    offs    = (int*)take((size_t)(N + 1) * 4);
    int*    hist    = (int*)take((size_t)C * B * 4);
    int*    chunkoff= (int*)take((size_t)C * B * 4);
    int*    bucktot = (int*)take((size_t)B * 4);

    k_ln1cvt<<<13 + (N + 3) / 4, 256, 0, stream>>>(x, ntyp, conv_gamma, conv_beta,
                                                   ybuf, W_rel, W_root, W_mlp, Wt, N);

    k_c1<<<C, 256, 0, stream>>>(edst, hist, E, B);
    k_c2<<<B, 128, 0, stream>>>(hist, chunkoff, bucktot, C, B);
    k_p1s<<<C, 256, 0, stream>>>(edst, esrc, etyp, bucktot, chunkoff, edata, E, B);
    k_p2<<<B, 256, 0, stream>>>(edata, bucktot, epack, offs, N, E, B);

    k_zagg<<<(N + 3) / 4, 256, 0, stream>>>(ybuf, offs, epack, zbuf, N);

    k_gm<<<(N + 63) / 64, 128, 0, stream>>>(ybuf, zbuf, Wt, x, ntyp,
                                            mlp_gamma, mlp_beta, b_mlp, out, N);
}